// Round 1
// baseline (336.165 us; speedup 1.0000x reference)
//
#include <hip/hip_runtime.h>
#include <hip/hip_bf16.h>

// Problem constants (B=4, T=2048, C=1024, H=16, HD=64)
#define BB 4
#define TT 2048
#define CC 1024
#define HH 16
#define HD 64

typedef _Float16 half8 __attribute__((ext_vector_type(8)));
typedef _Float16 half4 __attribute__((ext_vector_type(4)));
typedef _Float16 half2_t __attribute__((ext_vector_type(2)));
typedef __fp16 fp16x2 __attribute__((ext_vector_type(2)));
typedef float floatx4 __attribute__((ext_vector_type(4)));

// async global->LDS, 16B per lane (dest = wave-uniform base + lane*16)
__device__ __forceinline__ void async_cp16(const void* g, void* l) {
    __builtin_amdgcn_global_load_lds(
        (const __attribute__((address_space(1))) unsigned int*)g,
        (__attribute__((address_space(3))) unsigned int*)l,
        16, 0, 0);
}

// pack 4 f32 -> half4 via v_cvt_pkrtz_f16_f32 (2 ops instead of 4 cvt + 2 pack)
__device__ __forceinline__ half4 pack4(float p0, float p1, float p2, float p3) {
    fp16x2 lo = __builtin_amdgcn_cvt_pkrtz(p0, p1);
    fp16x2 hi = __builtin_amdgcn_cvt_pkrtz(p2, p3);
    return __builtin_bit_cast(half4, __builtin_shufflevector(lo, hi, 0, 1, 2, 3));
}

// max over 16 accumulator values, max3-friendly (nested fmaxf triples -> v_max3_f32)
__device__ __forceinline__ float max16(const floatx4 s[4]) {
    float a0 = fmaxf(fmaxf(s[0][0], s[0][1]), s[0][2]);
    float a1 = fmaxf(fmaxf(s[0][3], s[1][0]), s[1][1]);
    float a2 = fmaxf(fmaxf(s[1][2], s[1][3]), s[2][0]);
    float a3 = fmaxf(fmaxf(s[2][1], s[2][2]), s[2][3]);
    float a4 = fmaxf(fmaxf(s[3][0], s[3][1]), s[3][2]);
    float b0 = fmaxf(fmaxf(a0, a1), a2);
    float b1 = fmaxf(fmaxf(a3, a4), s[3][3]);
    return fmaxf(b0, b1);
}

// ---------------------------------------------------------------------------
// fp32 -> fp16 conversion, 8 elements/thread
// ---------------------------------------------------------------------------
__global__ void cvt_f32_f16(const float* __restrict__ src, _Float16* __restrict__ dst, int n) {
    int i = (blockIdx.x * blockDim.x + threadIdx.x) * 8;
    if (i < n) {
        float4 v0 = *(const float4*)(src + i);
        float4 v1 = *(const float4*)(src + i + 4);
        half8 h;
        h[0] = (_Float16)v0.x; h[1] = (_Float16)v0.y; h[2] = (_Float16)v0.z; h[3] = (_Float16)v0.w;
        h[4] = (_Float16)v1.x; h[5] = (_Float16)v1.y; h[6] = (_Float16)v1.z; h[7] = (_Float16)v1.w;
        *(half8*)(dst + i) = h;
    }
}

// ---------------------------------------------------------------------------
// NT GEMM, m97 structure: C[m][n] = sum_k A[m][k]*Bw[n][k] + bias[n]
// 128x128 tile, BK=32, 256 thr (4 waves 2x2), global_load_lds width-16
// staging into packed [128][32] LDS. mfma_f32_16x16x32_f16.
// EPI=0: scatter -> Q(scaled 0.125*log2e)/K/V fp16 [B*H, T, 64]
// EPI=1: fp32 -> c_out[m*N+n]
// ---------------------------------------------------------------------------
template <int EPI>
__global__ __launch_bounds__(256) void hgemm_nt(
    const _Float16* __restrict__ A, const _Float16* __restrict__ Bw,
    const float* __restrict__ bias,
    _Float16* __restrict__ q_out, _Float16* __restrict__ k_out, _Float16* __restrict__ v_out,
    float* __restrict__ c_out,
    int M, int N, int K)
{
    __shared__ __attribute__((aligned(16))) _Float16 As[128 * 32];  // packed, 8KB
    __shared__ __attribute__((aligned(16))) _Float16 Bs[128 * 32];

    const int tid  = threadIdx.x;
    const int lane = tid & 63;
    const int wave = tid >> 6;
    const int quad = lane >> 4;
    const int lc   = lane & 15;
    const int wr   = wave >> 1, wc = wave & 1;
    const size_t bm = (size_t)blockIdx.y * 128;
    const size_t bn = (size_t)blockIdx.x * 128;

    const int r0 = tid >> 2;        // 0..63
    const int ck = (tid & 3) * 8;   // 0,8,16,24

    const _Float16* Ap0 = A + (bm + r0) * (size_t)K + ck;
    const _Float16* Ap1 = A + (bm + 64 + r0) * (size_t)K + ck;
    const _Float16* Bp0 = Bw + (bn + r0) * (size_t)K + ck;
    const _Float16* Bp1 = Bw + (bn + 64 + r0) * (size_t)K + ck;
    _Float16* lA0 = As + tid * 8;
    _Float16* lA1 = As + 2048 + tid * 8;
    _Float16* lB0 = Bs + tid * 8;
    _Float16* lB1 = Bs + 2048 + tid * 8;

    floatx4 acc[4][4] = {};

    for (int kk = 0; kk < K; kk += 32) {
        __syncthreads();  // previous tile fully consumed
        async_cp16(Ap0 + kk, lA0);
        async_cp16(Ap1 + kk, lA1);
        async_cp16(Bp0 + kk, lB0);
        async_cp16(Bp1 + kk, lB1);
        __syncthreads();  // barrier drains vmcnt -> staging visible

        half8 af[4], bf[4];
#pragma unroll
        for (int mt = 0; mt < 4; mt++) af[mt] = *(const half8*)(As + (wr * 64 + mt * 16 + lc) * 32 + quad * 8);
#pragma unroll
        for (int nt = 0; nt < 4; nt++) bf[nt] = *(const half8*)(Bs + (wc * 64 + nt * 16 + lc) * 32 + quad * 8);
#pragma unroll
        for (int mt = 0; mt < 4; mt++)
#pragma unroll
            for (int nt = 0; nt < 4; nt++)
                acc[mt][nt] = __builtin_amdgcn_mfma_f32_16x16x32_f16(af[mt], bf[nt], acc[mt][nt], 0, 0, 0);
    }

#pragma unroll
    for (int mt = 0; mt < 4; mt++) {
        int mbase = (int)bm + wr * 64 + mt * 16 + quad * 4;
#pragma unroll
        for (int nt = 0; nt < 4; nt++) {
            int n = (int)bn + wc * 64 + nt * 16 + lc;
            float bv = bias[n];
#pragma unroll
            for (int r = 0; r < 4; r++) {
                float v = acc[mt][nt][r] + bv;
                int mm = mbase + r;
                if (EPI == 0) {
                    int seg = n >> 10;        // 0=Q 1=K 2=V
                    int cm  = n & 1023;
                    int h = cm >> 6, d = cm & 63;
                    int bb = mm >> 11, t = mm & 2047;
                    size_t dst = (((size_t)(bb * HH + h)) * TT + t) * HD + d;
                    // fold 1/sqrt(HD) * log2(e) into Q for exp2-based softmax
                    if (seg == 0)      q_out[dst] = (_Float16)(v * 0.18033688f);
                    else if (seg == 1) k_out[dst] = (_Float16)v;
                    else               v_out[dst] = (_Float16)v;
                } else {
                    c_out[(size_t)mm * N + n] = v;
                }
            }
        }
    }
}

// ---------------------------------------------------------------------------
// Flash attention, S^T formulation, 32 queries/wave. Grid (B*H, T/256),
// 512 thr = 8 waves, q-block 256. Key tile = 64.
//  S^T = K*Q^T (mfma 16x16x32, A=K rows shared across both query groups)
//  P^T C-regs == B-frag of mfma 16x16x16 -> PV with zero relayout
//  O^T += V^T * P^T ; V-frags shared across both query groups.
// VALU diet: T13 defer-max (skip O/l rescale unless tile max grows > 8 in
// log2 units; P bounded by 2^8=256, fine in fp16), v_cvt_pkrtz packing,
// v_max3 reduction tree.
// ---------------------------------------------------------------------------
__global__ __launch_bounds__(512) void attn_flash(
    const _Float16* __restrict__ Qp, const _Float16* __restrict__ Kp,
    const _Float16* __restrict__ Vp, _Float16* __restrict__ Op)
{
    __shared__ __attribute__((aligned(16))) _Float16 Ks[64][72];  // [key][dim]
    __shared__ __attribute__((aligned(16))) _Float16 Vt[64][76];  // [dim][key]

    const int bh   = blockIdx.x;   // 0..63 (b*16+h)
    const int qt   = blockIdx.y;   // 0..7
    const int tid  = threadIdx.x;
    const int lane = tid & 63;
    const int wave = tid >> 6;     // 0..7
    const int quad = lane >> 4;
    const int lc   = lane & 15;

    const size_t hb = (size_t)bh * TT * HD;
    const _Float16* Kh = Kp + hb;
    const _Float16* Vh = Vp + hb;

    // two query groups per wave; B-frag B[k=dim=quad*8+j][n=q=lc]
    const int q0row = qt * 256 + wave * 32 + lc;
    const int q1row = q0row + 16;
    half8 bq00 = *(const half8*)(Qp + hb + (size_t)q0row * HD + quad * 8);
    half8 bq01 = *(const half8*)(Qp + hb + (size_t)q0row * HD + 32 + quad * 8);
    half8 bq10 = *(const half8*)(Qp + hb + (size_t)q1row * HD + quad * 8);
    half8 bq11 = *(const half8*)(Qp + hb + (size_t)q1row * HD + 32 + quad * 8);

    floatx4 o0[4] = {}, o1[4] = {};  // O^T: dim = dt*16+quad*4+r, q = lc
    float m0 = -1e30f, l0 = 0.f, m1 = -1e30f, l1 = 0.f;

    // staging maps (512 threads)
    const int sk  = tid >> 3;          // K: key 0..63
    const int sc0 = (tid & 7) * 8;     // K: dim chunk
    const int vkp = tid >> 4;          // V: key pair 0..31
    const int vd4 = (tid & 15) * 4;    // V: dim group 0..60

    const _Float16* Kg  = Kh + (size_t)sk * HD + sc0;
    const _Float16* Vg0 = Vh + (size_t)(2 * vkp) * HD + vd4;
    const _Float16* Vg1 = Vg0 + HD;

    for (int kt = 0; kt < TT; kt += 64) {
        const size_t koff = (size_t)kt * HD;
        half8 kv  = *(const half8*)(Kg + koff);
        half4 va0 = *(const half4*)(Vg0 + koff);
        half4 vb0 = *(const half4*)(Vg1 + koff);
        __syncthreads();  // previous tile fully consumed
        *(half8*)&Ks[sk][sc0] = kv;
#pragma unroll
        for (int j = 0; j < 4; j++) {
            half2_t w; w[0] = va0[j]; w[1] = vb0[j];
            *(half2_t*)&Vt[vd4 + j][2 * vkp] = w;
        }
        __syncthreads();  // staging visible

        // ---- S^T = K * Q^T : 4 keytiles x 2 dim-halves x 2 q-groups ----
        floatx4 s0[4], s1[4];
        const floatx4 zf = {0.f, 0.f, 0.f, 0.f};
#pragma unroll
        for (int m = 0; m < 4; m++) {
            half8 a0 = *(const half8*)&Ks[m * 16 + lc][quad * 8];
            half8 a1 = *(const half8*)&Ks[m * 16 + lc][32 + quad * 8];
            s0[m] = __builtin_amdgcn_mfma_f32_16x16x32_f16(a0, bq00, zf, 0, 0, 0);
            s0[m] = __builtin_amdgcn_mfma_f32_16x16x32_f16(a1, bq01, s0[m], 0, 0, 0);
            s1[m] = __builtin_amdgcn_mfma_f32_16x16x32_f16(a0, bq10, zf, 0, 0, 0);
            s1[m] = __builtin_amdgcn_mfma_f32_16x16x32_f16(a1, bq11, s1[m], 0, 0, 0);
        }

        // ---- online softmax per group (exp2; scale folded into Q) ----
        half4 pf0[4], pf1[4];
        {
            float mx = max16(s0);
            mx = fmaxf(mx, __shfl_xor(mx, 16));
            mx = fmaxf(mx, __shfl_xor(mx, 32));
            // T13 defer-max: skip rescale when tile max within THR of running max
            const bool noresc = __all(mx <= m0 + 8.0f);
            const float mnew = noresc ? m0 : fmaxf(m0, mx);
            float rs = 0.f;
#pragma unroll
            for (int m = 0; m < 4; m++) {
                float p0 = exp2f(s0[m][0] - mnew);
                float p1 = exp2f(s0[m][1] - mnew);
                float p2 = exp2f(s0[m][2] - mnew);
                float p3 = exp2f(s0[m][3] - mnew);
                rs += (p0 + p1) + (p2 + p3);
                pf0[m] = pack4(p0, p1, p2, p3);
            }
            rs += __shfl_xor(rs, 16);
            rs += __shfl_xor(rs, 32);
            if (!noresc) {
                float al = exp2f(m0 - mnew);
                m0 = mnew;
                l0 *= al;
#pragma unroll
                for (int dt = 0; dt < 4; dt++) o0[dt] *= al;
            }
            l0 += rs;
        }
        {
            float mx = max16(s1);
            mx = fmaxf(mx, __shfl_xor(mx, 16));
            mx = fmaxf(mx, __shfl_xor(mx, 32));
            const bool noresc = __all(mx <= m1 + 8.0f);
            const float mnew = noresc ? m1 : fmaxf(m1, mx);
            float rs = 0.f;
#pragma unroll
            for (int m = 0; m < 4; m++) {
                float p0 = exp2f(s1[m][0] - mnew);
                float p1 = exp2f(s1[m][1] - mnew);
                float p2 = exp2f(s1[m][2] - mnew);
                float p3 = exp2f(s1[m][3] - mnew);
                rs += (p0 + p1) + (p2 + p3);
                pf1[m] = pack4(p0, p1, p2, p3);
            }
            rs += __shfl_xor(rs, 16);
            rs += __shfl_xor(rs, 32);
            if (!noresc) {
                float al = exp2f(m1 - mnew);
                m1 = mnew;
                l1 *= al;
#pragma unroll
                for (int dt = 0; dt < 4; dt++) o1[dt] *= al;
            }
            l1 += rs;
        }

        // ---- O^T += V^T * P^T : V-frags shared across both q-groups ----
#pragma unroll
        for (int dt = 0; dt < 4; dt++) {
            const _Float16* vr = &Vt[dt * 16 + lc][quad * 4];
#pragma unroll
            for (int m = 0; m < 4; m++) {
                half4 va = *(const half4*)(vr + m * 16);  // keys m*16+quad*4+{0..3}
                o0[dt] = __builtin_amdgcn_mfma_f32_16x16x16f16(va, pf0[m], o0[dt], 0, 0, 0);
                o1[dt] = __builtin_amdgcn_mfma_f32_16x16x16f16(va, pf1[m], o1[dt], 0, 0, 0);
            }
        }
    }

    // epilogue: O^T reg (dt, r) -> dim = dt*16 + quad*4 + r, t = q{0,1}row
    const int b = bh >> 4, h = bh & 15;
    {
        float inv = 1.0f / l0;
        size_t base = ((size_t)(b * TT + q0row)) * CC + h * HD;
#pragma unroll
        for (int dt = 0; dt < 4; dt++) {
            half4 hv;
#pragma unroll
            for (int r = 0; r < 4; r++) hv[r] = (_Float16)(o0[dt][r] * inv);
            *(half4*)(Op + base + dt * 16 + quad * 4) = hv;
        }
    }
    {
        float inv = 1.0f / l1;
        size_t base = ((size_t)(b * TT + q1row)) * CC + h * HD;
#pragma unroll
        for (int dt = 0; dt < 4; dt++) {
            half4 hv;
#pragma unroll
            for (int r = 0; r < 4; r++) hv[r] = (_Float16)(o1[dt][r] * inv);
            *(half4*)(Op + base + dt * 16 + quad * 4) = hv;
        }
    }
}

// ---------------------------------------------------------------------------
extern "C" void kernel_launch(void* const* d_in, const int* in_sizes, int n_in,
                              void* d_out, int out_size, void* d_ws, size_t ws_size,
                              hipStream_t stream) {
    const float* x      = (const float*)d_in[0];  // [B,T,C]
    const float* W_attn = (const float*)d_in[1];  // [3C,C]
    const float* b_attn = (const float*)d_in[2];  // [3C]
    const float* W_proj = (const float*)d_in[3];  // [C,C]
    const float* b_proj = (const float*)d_in[4];  // [C]
    float* out = (float*)d_out;

    const size_t SZ_XH  = (size_t)BB * TT * CC * 2;
    const size_t SZ_WA  = (size_t)3 * CC * CC * 2;
    const size_t SZ_WP  = (size_t)CC * CC * 2;
    const size_t SZ_QKV = (size_t)BB * HH * TT * HD * 2;
    size_t off = 0;
    _Float16* xh  = (_Float16*)((char*)d_ws + off); off += SZ_XH;
    _Float16* wah = (_Float16*)((char*)d_ws + off); off += SZ_WA;
    _Float16* wph = (_Float16*)((char*)d_ws + off); off += SZ_WP;
    _Float16* Qh  = (_Float16*)((char*)d_ws + off); off += SZ_QKV;
    _Float16* Kh  = (_Float16*)((char*)d_ws + off); off += SZ_QKV;
    _Float16* Vh  = (_Float16*)((char*)d_ws + off); off += SZ_QKV;
    _Float16* Ah  = (_Float16*)((char*)d_ws + off); off += SZ_XH;
    if (ws_size < off) return;

    const int NX  = BB * TT * CC;
    const int NWA = 3 * CC * CC;
    const int NWP = CC * CC;
    cvt_f32_f16<<<NX / 8 / 256, 256, 0, stream>>>(x, xh, NX);
    cvt_f32_f16<<<NWA / 8 / 256, 256, 0, stream>>>(W_attn, wah, NWA);
    cvt_f32_f16<<<NWP / 8 / 256, 256, 0, stream>>>(W_proj, wph, NWP);

    hgemm_nt<0><<<dim3(3 * CC / 128, BB * TT / 128), 256, 0, stream>>>(
        xh, wah, b_attn, Qh, Kh, Vh, nullptr, BB * TT, 3 * CC, CC);

    attn_flash<<<dim3(BB * HH, TT / 256), 512, 0, stream>>>(Qh, Kh, Vh, Ah);

    hgemm_nt<1><<<dim3(CC / 128, BB * TT / 128), 256, 0, stream>>>(
        Ah, wph, b_proj, nullptr, nullptr, nullptr, out, BB * TT, CC, CC);
}

// Round 2
// 295.533 us; speedup vs baseline: 1.1375x; 1.1375x over previous
//
#include <hip/hip_runtime.h>
#include <hip/hip_bf16.h>

// Problem constants (B=4, T=2048, C=1024, H=16, HD=64)
#define BB 4
#define TT 2048
#define CC 1024
#define HH 16
#define HD 64

typedef _Float16 half8 __attribute__((ext_vector_type(8)));
typedef _Float16 half4 __attribute__((ext_vector_type(4)));
typedef _Float16 half2_t __attribute__((ext_vector_type(2)));
typedef __fp16 fp16x2 __attribute__((ext_vector_type(2)));
typedef float floatx4 __attribute__((ext_vector_type(4)));

// async global->LDS, 16B per lane (dest = wave-uniform base + lane*16)
__device__ __forceinline__ void async_cp16(const void* g, void* l) {
    __builtin_amdgcn_global_load_lds(
        (const __attribute__((address_space(1))) unsigned int*)g,
        (__attribute__((address_space(3))) unsigned int*)l,
        16, 0, 0);
}

// raw v_exp_f32 — skips OCML's range/denormal guard sequence (~5 VALU ops per
// call). Args here are <= 8 (defer-max THR) so no overflow; very negative
// args underflow to 0 in HW which is exactly softmax semantics.
__device__ __forceinline__ float exp2_raw(float x) {
    return __builtin_amdgcn_exp2f(x);
}

// pack 4 f32 -> half4 via v_cvt_pkrtz_f16_f32
__device__ __forceinline__ half4 pack4(float p0, float p1, float p2, float p3) {
    fp16x2 lo = __builtin_amdgcn_cvt_pkrtz(p0, p1);
    fp16x2 hi = __builtin_amdgcn_cvt_pkrtz(p2, p3);
    return __builtin_bit_cast(half4, __builtin_shufflevector(lo, hi, 0, 1, 2, 3));
}

// max over 16 accumulator values, max3-friendly (nested fmaxf triples -> v_max3_f32)
__device__ __forceinline__ float max16(const floatx4 s[4]) {
    float a0 = fmaxf(fmaxf(s[0][0], s[0][1]), s[0][2]);
    float a1 = fmaxf(fmaxf(s[0][3], s[1][0]), s[1][1]);
    float a2 = fmaxf(fmaxf(s[1][2], s[1][3]), s[2][0]);
    float a3 = fmaxf(fmaxf(s[2][1], s[2][2]), s[2][3]);
    float a4 = fmaxf(fmaxf(s[3][0], s[3][1]), s[3][2]);
    float b0 = fmaxf(fmaxf(a0, a1), a2);
    float b1 = fmaxf(fmaxf(a3, a4), s[3][3]);
    return fmaxf(b0, b1);
}

// ---------------------------------------------------------------------------
// fp32 -> fp16 conversion, 8 elements/thread
// ---------------------------------------------------------------------------
__global__ void cvt_f32_f16(const float* __restrict__ src, _Float16* __restrict__ dst, int n) {
    int i = (blockIdx.x * blockDim.x + threadIdx.x) * 8;
    if (i < n) {
        float4 v0 = *(const float4*)(src + i);
        float4 v1 = *(const float4*)(src + i + 4);
        half8 h;
        h[0] = (_Float16)v0.x; h[1] = (_Float16)v0.y; h[2] = (_Float16)v0.z; h[3] = (_Float16)v0.w;
        h[4] = (_Float16)v1.x; h[5] = (_Float16)v1.y; h[6] = (_Float16)v1.z; h[7] = (_Float16)v1.w;
        *(half8*)(dst + i) = h;
    }
}

// ---------------------------------------------------------------------------
// NT GEMM, m97 structure: C[m][n] = sum_k A[m][k]*Bw[n][k] + bias[n]
// 128x128 tile, BK=32, 256 thr (4 waves 2x2), global_load_lds width-16
// staging into packed [128][32] LDS. mfma_f32_16x16x32_f16.
// EPI=0: scatter -> Q(scaled 0.125*log2e)/K/V fp16 [B*H, T, 64]
// EPI=1: fp32 -> c_out[m*N+n]
// ---------------------------------------------------------------------------
template <int EPI>
__global__ __launch_bounds__(256) void hgemm_nt(
    const _Float16* __restrict__ A, const _Float16* __restrict__ Bw,
    const float* __restrict__ bias,
    _Float16* __restrict__ q_out, _Float16* __restrict__ k_out, _Float16* __restrict__ v_out,
    float* __restrict__ c_out,
    int M, int N, int K)
{
    __shared__ __attribute__((aligned(16))) _Float16 As[128 * 32];  // packed, 8KB
    __shared__ __attribute__((aligned(16))) _Float16 Bs[128 * 32];

    const int tid  = threadIdx.x;
    const int lane = tid & 63;
    const int wave = tid >> 6;
    const int quad = lane >> 4;
    const int lc   = lane & 15;
    const int wr   = wave >> 1, wc = wave & 1;
    const size_t bm = (size_t)blockIdx.y * 128;
    const size_t bn = (size_t)blockIdx.x * 128;

    const int r0 = tid >> 2;        // 0..63
    const int ck = (tid & 3) * 8;   // 0,8,16,24

    const _Float16* Ap0 = A + (bm + r0) * (size_t)K + ck;
    const _Float16* Ap1 = A + (bm + 64 + r0) * (size_t)K + ck;
    const _Float16* Bp0 = Bw + (bn + r0) * (size_t)K + ck;
    const _Float16* Bp1 = Bw + (bn + 64 + r0) * (size_t)K + ck;
    _Float16* lA0 = As + tid * 8;
    _Float16* lA1 = As + 2048 + tid * 8;
    _Float16* lB0 = Bs + tid * 8;
    _Float16* lB1 = Bs + 2048 + tid * 8;

    floatx4 acc[4][4] = {};

    for (int kk = 0; kk < K; kk += 32) {
        __syncthreads();  // previous tile fully consumed
        async_cp16(Ap0 + kk, lA0);
        async_cp16(Ap1 + kk, lA1);
        async_cp16(Bp0 + kk, lB0);
        async_cp16(Bp1 + kk, lB1);
        __syncthreads();  // barrier drains vmcnt -> staging visible

        half8 af[4], bf[4];
#pragma unroll
        for (int mt = 0; mt < 4; mt++) af[mt] = *(const half8*)(As + (wr * 64 + mt * 16 + lc) * 32 + quad * 8);
#pragma unroll
        for (int nt = 0; nt < 4; nt++) bf[nt] = *(const half8*)(Bs + (wc * 64 + nt * 16 + lc) * 32 + quad * 8);
#pragma unroll
        for (int mt = 0; mt < 4; mt++)
#pragma unroll
            for (int nt = 0; nt < 4; nt++)
                acc[mt][nt] = __builtin_amdgcn_mfma_f32_16x16x32_f16(af[mt], bf[nt], acc[mt][nt], 0, 0, 0);
    }

#pragma unroll
    for (int mt = 0; mt < 4; mt++) {
        int mbase = (int)bm + wr * 64 + mt * 16 + quad * 4;
#pragma unroll
        for (int nt = 0; nt < 4; nt++) {
            int n = (int)bn + wc * 64 + nt * 16 + lc;
            float bv = bias[n];
#pragma unroll
            for (int r = 0; r < 4; r++) {
                float v = acc[mt][nt][r] + bv;
                int mm = mbase + r;
                if (EPI == 0) {
                    int seg = n >> 10;        // 0=Q 1=K 2=V
                    int cm  = n & 1023;
                    int h = cm >> 6, d = cm & 63;
                    int bb = mm >> 11, t = mm & 2047;
                    size_t dst = (((size_t)(bb * HH + h)) * TT + t) * HD + d;
                    // fold 1/sqrt(HD) * log2(e) into Q for exp2-based softmax
                    if (seg == 0)      q_out[dst] = (_Float16)(v * 0.18033688f);
                    else if (seg == 1) k_out[dst] = (_Float16)v;
                    else               v_out[dst] = (_Float16)v;
                } else {
                    c_out[(size_t)mm * N + n] = v;
                }
            }
        }
    }
}

// ---------------------------------------------------------------------------
// Flash attention, S^T formulation, 32 queries/wave. Grid (B*H, T/256),
// 512 thr = 8 waves, q-block 256. Key tile = 64.
//  S^T = K*Q^T (mfma 16x16x32, A=K rows shared across both query groups)
//  P^T C-regs == B-frag of mfma 16x16x16 -> PV with zero relayout
//  O^T += V^T * P^T ; V-frags shared across both query groups.
// VALU diet: raw v_exp_f32 (no OCML guard), T13 defer-max, pkrtz packing,
// max3 reduction tree.
// ---------------------------------------------------------------------------
__global__ __launch_bounds__(512) void attn_flash(
    const _Float16* __restrict__ Qp, const _Float16* __restrict__ Kp,
    const _Float16* __restrict__ Vp, _Float16* __restrict__ Op)
{
    __shared__ __attribute__((aligned(16))) _Float16 Ks[64][72];  // [key][dim]
    __shared__ __attribute__((aligned(16))) _Float16 Vt[64][76];  // [dim][key]

    const int bh   = blockIdx.x;   // 0..63 (b*16+h)
    const int qt   = blockIdx.y;   // 0..7
    const int tid  = threadIdx.x;
    const int lane = tid & 63;
    const int wave = tid >> 6;     // 0..7
    const int quad = lane >> 4;
    const int lc   = lane & 15;

    const size_t hb = (size_t)bh * TT * HD;
    const _Float16* Kh = Kp + hb;
    const _Float16* Vh = Vp + hb;

    // two query groups per wave; B-frag B[k=dim=quad*8+j][n=q=lc]
    const int q0row = qt * 256 + wave * 32 + lc;
    const int q1row = q0row + 16;
    half8 bq00 = *(const half8*)(Qp + hb + (size_t)q0row * HD + quad * 8);
    half8 bq01 = *(const half8*)(Qp + hb + (size_t)q0row * HD + 32 + quad * 8);
    half8 bq10 = *(const half8*)(Qp + hb + (size_t)q1row * HD + quad * 8);
    half8 bq11 = *(const half8*)(Qp + hb + (size_t)q1row * HD + 32 + quad * 8);

    floatx4 o0[4] = {}, o1[4] = {};  // O^T: dim = dt*16+quad*4+r, q = lc
    float m0 = -1e30f, l0 = 0.f, m1 = -1e30f, l1 = 0.f;

    // staging maps (512 threads)
    const int sk  = tid >> 3;          // K: key 0..63
    const int sc0 = (tid & 7) * 8;     // K: dim chunk
    const int vkp = tid >> 4;          // V: key pair 0..31
    const int vd4 = (tid & 15) * 4;    // V: dim group 0..60

    const _Float16* Kg  = Kh + (size_t)sk * HD + sc0;
    const _Float16* Vg0 = Vh + (size_t)(2 * vkp) * HD + vd4;
    const _Float16* Vg1 = Vg0 + HD;

    for (int kt = 0; kt < TT; kt += 64) {
        const size_t koff = (size_t)kt * HD;
        half8 kv  = *(const half8*)(Kg + koff);
        half4 va0 = *(const half4*)(Vg0 + koff);
        half4 vb0 = *(const half4*)(Vg1 + koff);
        __syncthreads();  // previous tile fully consumed
        *(half8*)&Ks[sk][sc0] = kv;
#pragma unroll
        for (int j = 0; j < 4; j++) {
            half2_t w; w[0] = va0[j]; w[1] = vb0[j];
            *(half2_t*)&Vt[vd4 + j][2 * vkp] = w;
        }
        __syncthreads();  // staging visible

        // ---- S^T = K * Q^T : 4 keytiles x 2 dim-halves x 2 q-groups ----
        floatx4 s0[4], s1[4];
        const floatx4 zf = {0.f, 0.f, 0.f, 0.f};
#pragma unroll
        for (int m = 0; m < 4; m++) {
            half8 a0 = *(const half8*)&Ks[m * 16 + lc][quad * 8];
            half8 a1 = *(const half8*)&Ks[m * 16 + lc][32 + quad * 8];
            s0[m] = __builtin_amdgcn_mfma_f32_16x16x32_f16(a0, bq00, zf, 0, 0, 0);
            s0[m] = __builtin_amdgcn_mfma_f32_16x16x32_f16(a1, bq01, s0[m], 0, 0, 0);
            s1[m] = __builtin_amdgcn_mfma_f32_16x16x32_f16(a0, bq10, zf, 0, 0, 0);
            s1[m] = __builtin_amdgcn_mfma_f32_16x16x32_f16(a1, bq11, s1[m], 0, 0, 0);
        }

        // ---- online softmax per group (raw exp2; scale folded into Q) ----
        half4 pf0[4], pf1[4];
        {
            float mx = max16(s0);
            mx = fmaxf(mx, __shfl_xor(mx, 16));
            mx = fmaxf(mx, __shfl_xor(mx, 32));
            // T13 defer-max: skip rescale when tile max within THR of running max
            const bool noresc = __all(mx <= m0 + 8.0f);
            const float mnew = noresc ? m0 : fmaxf(m0, mx);
            float rs = 0.f;
#pragma unroll
            for (int m = 0; m < 4; m++) {
                float p0 = exp2_raw(s0[m][0] - mnew);
                float p1 = exp2_raw(s0[m][1] - mnew);
                float p2 = exp2_raw(s0[m][2] - mnew);
                float p3 = exp2_raw(s0[m][3] - mnew);
                rs += (p0 + p1) + (p2 + p3);
                pf0[m] = pack4(p0, p1, p2, p3);
            }
            rs += __shfl_xor(rs, 16);
            rs += __shfl_xor(rs, 32);
            if (!noresc) {
                float al = exp2_raw(m0 - mnew);
                m0 = mnew;
                l0 *= al;
#pragma unroll
                for (int dt = 0; dt < 4; dt++) o0[dt] *= al;
            }
            l0 += rs;
        }
        {
            float mx = max16(s1);
            mx = fmaxf(mx, __shfl_xor(mx, 16));
            mx = fmaxf(mx, __shfl_xor(mx, 32));
            const bool noresc = __all(mx <= m1 + 8.0f);
            const float mnew = noresc ? m1 : fmaxf(m1, mx);
            float rs = 0.f;
#pragma unroll
            for (int m = 0; m < 4; m++) {
                float p0 = exp2_raw(s1[m][0] - mnew);
                float p1 = exp2_raw(s1[m][1] - mnew);
                float p2 = exp2_raw(s1[m][2] - mnew);
                float p3 = exp2_raw(s1[m][3] - mnew);
                rs += (p0 + p1) + (p2 + p3);
                pf1[m] = pack4(p0, p1, p2, p3);
            }
            rs += __shfl_xor(rs, 16);
            rs += __shfl_xor(rs, 32);
            if (!noresc) {
                float al = exp2_raw(m1 - mnew);
                m1 = mnew;
                l1 *= al;
#pragma unroll
                for (int dt = 0; dt < 4; dt++) o1[dt] *= al;
            }
            l1 += rs;
        }

        // ---- O^T += V^T * P^T : V-frags shared across both q-groups ----
#pragma unroll
        for (int dt = 0; dt < 4; dt++) {
            const _Float16* vr = &Vt[dt * 16 + lc][quad * 4];
#pragma unroll
            for (int m = 0; m < 4; m++) {
                half4 va = *(const half4*)(vr + m * 16);  // keys m*16+quad*4+{0..3}
                o0[dt] = __builtin_amdgcn_mfma_f32_16x16x16f16(va, pf0[m], o0[dt], 0, 0, 0);
                o1[dt] = __builtin_amdgcn_mfma_f32_16x16x16f16(va, pf1[m], o1[dt], 0, 0, 0);
            }
        }
    }

    // epilogue: O^T reg (dt, r) -> dim = dt*16 + quad*4 + r, t = q{0,1}row
    const int b = bh >> 4, h = bh & 15;
    {
        float inv = __builtin_amdgcn_rcpf(l0);
        size_t base = ((size_t)(b * TT + q0row)) * CC + h * HD;
#pragma unroll
        for (int dt = 0; dt < 4; dt++) {
            half4 hv;
#pragma unroll
            for (int r = 0; r < 4; r++) hv[r] = (_Float16)(o0[dt][r] * inv);
            *(half4*)(Op + base + dt * 16 + quad * 4) = hv;
        }
    }
    {
        float inv = __builtin_amdgcn_rcpf(l1);
        size_t base = ((size_t)(b * TT + q1row)) * CC + h * HD;
#pragma unroll
        for (int dt = 0; dt < 4; dt++) {
            half4 hv;
#pragma unroll
            for (int r = 0; r < 4; r++) hv[r] = (_Float16)(o1[dt][r] * inv);
            *(half4*)(Op + base + dt * 16 + quad * 4) = hv;
        }
    }
}

// ---------------------------------------------------------------------------
extern "C" void kernel_launch(void* const* d_in, const int* in_sizes, int n_in,
                              void* d_out, int out_size, void* d_ws, size_t ws_size,
                              hipStream_t stream) {
    const float* x      = (const float*)d_in[0];  // [B,T,C]
    const float* W_attn = (const float*)d_in[1];  // [3C,C]
    const float* b_attn = (const float*)d_in[2];  // [3C]
    const float* W_proj = (const float*)d_in[3];  // [C,C]
    const float* b_proj = (const float*)d_in[4];  // [C]
    float* out = (float*)d_out;

    const size_t SZ_XH  = (size_t)BB * TT * CC * 2;
    const size_t SZ_WA  = (size_t)3 * CC * CC * 2;
    const size_t SZ_WP  = (size_t)CC * CC * 2;
    const size_t SZ_QKV = (size_t)BB * HH * TT * HD * 2;
    size_t off = 0;
    _Float16* xh  = (_Float16*)((char*)d_ws + off); off += SZ_XH;
    _Float16* wah = (_Float16*)((char*)d_ws + off); off += SZ_WA;
    _Float16* wph = (_Float16*)((char*)d_ws + off); off += SZ_WP;
    _Float16* Qh  = (_Float16*)((char*)d_ws + off); off += SZ_QKV;
    _Float16* Kh  = (_Float16*)((char*)d_ws + off); off += SZ_QKV;
    _Float16* Vh  = (_Float16*)((char*)d_ws + off); off += SZ_QKV;
    _Float16* Ah  = (_Float16*)((char*)d_ws + off); off += SZ_XH;
    if (ws_size < off) return;

    const int NX  = BB * TT * CC;
    const int NWA = 3 * CC * CC;
    const int NWP = CC * CC;
    cvt_f32_f16<<<NX / 8 / 256, 256, 0, stream>>>(x, xh, NX);
    cvt_f32_f16<<<NWA / 8 / 256, 256, 0, stream>>>(W_attn, wah, NWA);
    cvt_f32_f16<<<NWP / 8 / 256, 256, 0, stream>>>(W_proj, wph, NWP);

    hgemm_nt<0><<<dim3(3 * CC / 128, BB * TT / 128), 256, 0, stream>>>(
        xh, wah, b_attn, Qh, Kh, Vh, nullptr, BB * TT, 3 * CC, CC);

    attn_flash<<<dim3(BB * HH, TT / 256), 512, 0, stream>>>(Qh, Kh, Vh, Ah);

    hgemm_nt<1><<<dim3(CC / 128, BB * TT / 128), 256, 0, stream>>>(
        Ah, wph, b_proj, nullptr, nullptr, nullptr, out, BB * TT, CC, CC);
}

// Round 4
// 291.857 us; speedup vs baseline: 1.1518x; 1.0126x over previous
//
#include <hip/hip_runtime.h>
#include <hip/hip_bf16.h>

// Problem constants (B=4, T=2048, C=1024, H=16, HD=64)
#define BB 4
#define TT 2048
#define CC 1024
#define HH 16
#define HD 64

typedef _Float16 half8 __attribute__((ext_vector_type(8)));
typedef _Float16 half4 __attribute__((ext_vector_type(4)));
typedef _Float16 half2_t __attribute__((ext_vector_type(2)));
typedef __fp16 fp16x2 __attribute__((ext_vector_type(2)));
typedef float floatx4 __attribute__((ext_vector_type(4)));

// async global->LDS, 16B per lane (dest = wave-uniform base + lane*16)
__device__ __forceinline__ void async_cp16(const void* g, void* l) {
    __builtin_amdgcn_global_load_lds(
        (const __attribute__((address_space(1))) unsigned int*)g,
        (__attribute__((address_space(3))) unsigned int*)l,
        16, 0, 0);
}

// raw v_exp_f32 — skips OCML's range/denormal guard sequence. Args are
// <= 8 (defer-max THR) so no overflow; very negative args underflow to 0
// in HW which is exactly softmax semantics.
__device__ __forceinline__ float exp2_raw(float x) {
    return __builtin_amdgcn_exp2f(x);
}

// pack 4 f32 -> half4 via v_cvt_pkrtz_f16_f32
__device__ __forceinline__ half4 pack4(float p0, float p1, float p2, float p3) {
    fp16x2 lo = __builtin_amdgcn_cvt_pkrtz(p0, p1);
    fp16x2 hi = __builtin_amdgcn_cvt_pkrtz(p2, p3);
    return __builtin_bit_cast(half4, __builtin_shufflevector(lo, hi, 0, 1, 2, 3));
}

// max over 16 accumulator values, max3-friendly (nested fmaxf triples -> v_max3_f32)
__device__ __forceinline__ float max16(const floatx4 s[4]) {
    float a0 = fmaxf(fmaxf(s[0][0], s[0][1]), s[0][2]);
    float a1 = fmaxf(fmaxf(s[0][3], s[1][0]), s[1][1]);
    float a2 = fmaxf(fmaxf(s[1][2], s[1][3]), s[2][0]);
    float a3 = fmaxf(fmaxf(s[2][1], s[2][2]), s[2][3]);
    float a4 = fmaxf(fmaxf(s[3][0], s[3][1]), s[3][2]);
    float b0 = fmaxf(fmaxf(a0, a1), a2);
    float b1 = fmaxf(fmaxf(a3, a4), s[3][3]);
    return fmaxf(b0, b1);
}

// ---------------------------------------------------------------------------
// fp32 -> fp16 conversion, 8 elements/thread
// ---------------------------------------------------------------------------
__global__ void cvt_f32_f16(const float* __restrict__ src, _Float16* __restrict__ dst, int n) {
    int i = (blockIdx.x * blockDim.x + threadIdx.x) * 8;
    if (i < n) {
        float4 v0 = *(const float4*)(src + i);
        float4 v1 = *(const float4*)(src + i + 4);
        half8 h;
        h[0] = (_Float16)v0.x; h[1] = (_Float16)v0.y; h[2] = (_Float16)v0.z; h[3] = (_Float16)v0.w;
        h[4] = (_Float16)v1.x; h[5] = (_Float16)v1.y; h[6] = (_Float16)v1.z; h[7] = (_Float16)v1.w;
        *(half8*)(dst + i) = h;
    }
}

// ---------------------------------------------------------------------------
// NT GEMM: C[m][n] = sum_k A[m][k]*Bw[n][k] + bias[n]
// 128x128 tile, BK=64, 256 thr (4 waves 2x2), global_load_lds width-16.
// LDS: two K-half sub-tiles, layout [h][row][32], h = K-half.
//   element offset = h*4096 + row*32 + col   (4096 ELEMENTS = 8KB per half)
// ds_read bank pattern per half is identical to the BK=32 version (row
// stride 64B). 32 MFMA + 8 loads per barrier-pair — halves barrier-drain
// count per FLOP vs BK=32.
// EPI=0: scatter -> Q(scaled 0.125*log2e)/K/V fp16 [B*H, T, 64]
// EPI=1: fp32 -> c_out[m*N+n]
// ---------------------------------------------------------------------------
template <int EPI>
__global__ __launch_bounds__(256) void hgemm_nt(
    const _Float16* __restrict__ A, const _Float16* __restrict__ Bw,
    const float* __restrict__ bias,
    _Float16* __restrict__ q_out, _Float16* __restrict__ k_out, _Float16* __restrict__ v_out,
    float* __restrict__ c_out,
    int M, int N, int K)
{
    __shared__ __attribute__((aligned(16))) _Float16 As[2 * 128 * 32];  // 16KB
    __shared__ __attribute__((aligned(16))) _Float16 Bs[2 * 128 * 32];  // 16KB

    const int tid  = threadIdx.x;
    const int lane = tid & 63;
    const int wave = tid >> 6;
    const int quad = lane >> 4;
    const int lc   = lane & 15;
    const int wr   = wave >> 1, wc = wave & 1;
    const size_t bm = (size_t)blockIdx.y * 128;
    const size_t bn = (size_t)blockIdx.x * 128;

    const int r0 = tid >> 2;        // 0..63 (row within 64-row block)
    const int ck = (tid & 3) * 8;   // 0,8,16,24 (col within 32-col half)

    const _Float16* Ap = A + (bm + r0) * (size_t)K + ck;
    const _Float16* Bp = Bw + (bn + r0) * (size_t)K + ck;
    // dst: rows 0..63 h0 -> elem 0..2047; rows 64..127 h0 -> 2048..4095;
    //      h1 adds +4096 elements
    _Float16* lA = As + tid * 8;
    _Float16* lB = Bs + tid * 8;
    const size_t rstep = (size_t)64 * K;

    floatx4 acc[4][4] = {};

    for (int kk = 0; kk < K; kk += 64) {
        __syncthreads();  // previous tile fully consumed
        async_cp16(Ap + kk, lA);
        async_cp16(Ap + kk + rstep, lA + 2048);
        async_cp16(Ap + kk + 32, lA + 4096);
        async_cp16(Ap + kk + 32 + rstep, lA + 4096 + 2048);
        async_cp16(Bp + kk, lB);
        async_cp16(Bp + kk + rstep, lB + 2048);
        async_cp16(Bp + kk + 32, lB + 4096);
        async_cp16(Bp + kk + 32 + rstep, lB + 4096 + 2048);
        __syncthreads();  // barrier drains vmcnt -> staging visible

#pragma unroll
        for (int h = 0; h < 2; h++) {
            half8 af[4], bf[4];
#pragma unroll
            for (int mt = 0; mt < 4; mt++)
                af[mt] = *(const half8*)(As + h * 4096 + (wr * 64 + mt * 16 + lc) * 32 + quad * 8);
#pragma unroll
            for (int nt = 0; nt < 4; nt++)
                bf[nt] = *(const half8*)(Bs + h * 4096 + (wc * 64 + nt * 16 + lc) * 32 + quad * 8);
#pragma unroll
            for (int mt = 0; mt < 4; mt++)
#pragma unroll
                for (int nt = 0; nt < 4; nt++)
                    acc[mt][nt] = __builtin_amdgcn_mfma_f32_16x16x32_f16(af[mt], bf[nt], acc[mt][nt], 0, 0, 0);
        }
    }

#pragma unroll
    for (int mt = 0; mt < 4; mt++) {
        int mbase = (int)bm + wr * 64 + mt * 16 + quad * 4;
#pragma unroll
        for (int nt = 0; nt < 4; nt++) {
            int n = (int)bn + wc * 64 + nt * 16 + lc;
            float bv = bias[n];
#pragma unroll
            for (int r = 0; r < 4; r++) {
                float v = acc[mt][nt][r] + bv;
                int mm = mbase + r;
                if (EPI == 0) {
                    int seg = n >> 10;        // 0=Q 1=K 2=V
                    int cm  = n & 1023;
                    int h = cm >> 6, d = cm & 63;
                    int bb = mm >> 11, t = mm & 2047;
                    size_t dst = (((size_t)(bb * HH + h)) * TT + t) * HD + d;
                    // fold 1/sqrt(HD) * log2(e) into Q for exp2-based softmax
                    if (seg == 0)      q_out[dst] = (_Float16)(v * 0.18033688f);
                    else if (seg == 1) k_out[dst] = (_Float16)v;
                    else               v_out[dst] = (_Float16)v;
                } else {
                    c_out[(size_t)mm * N + n] = v;
                }
            }
        }
    }
}

// ---------------------------------------------------------------------------
// Flash attention, S^T formulation, 32 queries/wave. Grid (B*H, T/256),
// 512 thr = 8 waves, q-block 256. Key tile = 64.
//  S^T = K*Q^T (mfma 16x16x32, A=K rows shared across both query groups)
//  P^T C-regs == B-frag of mfma 16x16x16 -> PV with zero relayout
//  O^T += V^T * P^T ; V-frags shared across both query groups.
// VALU diet: raw v_exp_f32, T13 defer-max, pkrtz packing, max3 tree.
// T5: s_setprio(1) around MFMA clusters.
// ---------------------------------------------------------------------------
__global__ __launch_bounds__(512) void attn_flash(
    const _Float16* __restrict__ Qp, const _Float16* __restrict__ Kp,
    const _Float16* __restrict__ Vp, _Float16* __restrict__ Op)
{
    __shared__ __attribute__((aligned(16))) _Float16 Ks[64][72];  // [key][dim]
    __shared__ __attribute__((aligned(16))) _Float16 Vt[64][76];  // [dim][key]

    const int bh   = blockIdx.x;   // 0..63 (b*16+h)
    const int qt   = blockIdx.y;   // 0..7
    const int tid  = threadIdx.x;
    const int lane = tid & 63;
    const int wave = tid >> 6;     // 0..7
    const int quad = lane >> 4;
    const int lc   = lane & 15;

    const size_t hb = (size_t)bh * TT * HD;
    const _Float16* Kh = Kp + hb;
    const _Float16* Vh = Vp + hb;

    // two query groups per wave; B-frag B[k=dim=quad*8+j][n=q=lc]
    const int q0row = qt * 256 + wave * 32 + lc;
    const int q1row = q0row + 16;
    half8 bq00 = *(const half8*)(Qp + hb + (size_t)q0row * HD + quad * 8);
    half8 bq01 = *(const half8*)(Qp + hb + (size_t)q0row * HD + 32 + quad * 8);
    half8 bq10 = *(const half8*)(Qp + hb + (size_t)q1row * HD + quad * 8);
    half8 bq11 = *(const half8*)(Qp + hb + (size_t)q1row * HD + 32 + quad * 8);

    floatx4 o0[4] = {}, o1[4] = {};  // O^T: dim = dt*16+quad*4+r, q = lc
    float m0 = -1e30f, l0 = 0.f, m1 = -1e30f, l1 = 0.f;

    // staging maps (512 threads)
    const int sk  = tid >> 3;          // K: key 0..63
    const int sc0 = (tid & 7) * 8;     // K: dim chunk
    const int vkp = tid >> 4;          // V: key pair 0..31
    const int vd4 = (tid & 15) * 4;    // V: dim group 0..60

    const _Float16* Kg  = Kh + (size_t)sk * HD + sc0;
    const _Float16* Vg0 = Vh + (size_t)(2 * vkp) * HD + vd4;
    const _Float16* Vg1 = Vg0 + HD;

    for (int kt = 0; kt < TT; kt += 64) {
        const size_t koff = (size_t)kt * HD;
        half8 kv  = *(const half8*)(Kg + koff);
        half4 va0 = *(const half4*)(Vg0 + koff);
        half4 vb0 = *(const half4*)(Vg1 + koff);
        __syncthreads();  // previous tile fully consumed
        *(half8*)&Ks[sk][sc0] = kv;
#pragma unroll
        for (int j = 0; j < 4; j++) {
            half2_t w; w[0] = va0[j]; w[1] = vb0[j];
            *(half2_t*)&Vt[vd4 + j][2 * vkp] = w;
        }
        __syncthreads();  // staging visible

        // ---- S^T = K * Q^T : 4 keytiles x 2 dim-halves x 2 q-groups ----
        floatx4 s0[4], s1[4];
        const floatx4 zf = {0.f, 0.f, 0.f, 0.f};
        __builtin_amdgcn_s_setprio(1);
#pragma unroll
        for (int m = 0; m < 4; m++) {
            half8 a0 = *(const half8*)&Ks[m * 16 + lc][quad * 8];
            half8 a1 = *(const half8*)&Ks[m * 16 + lc][32 + quad * 8];
            s0[m] = __builtin_amdgcn_mfma_f32_16x16x32_f16(a0, bq00, zf, 0, 0, 0);
            s0[m] = __builtin_amdgcn_mfma_f32_16x16x32_f16(a1, bq01, s0[m], 0, 0, 0);
            s1[m] = __builtin_amdgcn_mfma_f32_16x16x32_f16(a0, bq10, zf, 0, 0, 0);
            s1[m] = __builtin_amdgcn_mfma_f32_16x16x32_f16(a1, bq11, s1[m], 0, 0, 0);
        }
        __builtin_amdgcn_s_setprio(0);

        // ---- online softmax per group (raw exp2; scale folded into Q) ----
        half4 pf0[4], pf1[4];
        {
            float mx = max16(s0);
            mx = fmaxf(mx, __shfl_xor(mx, 16));
            mx = fmaxf(mx, __shfl_xor(mx, 32));
            // T13 defer-max: skip rescale when tile max within THR of running max
            const bool noresc = __all(mx <= m0 + 8.0f);
            const float mnew = noresc ? m0 : fmaxf(m0, mx);
            float rs = 0.f;
#pragma unroll
            for (int m = 0; m < 4; m++) {
                float p0 = exp2_raw(s0[m][0] - mnew);
                float p1 = exp2_raw(s0[m][1] - mnew);
                float p2 = exp2_raw(s0[m][2] - mnew);
                float p3 = exp2_raw(s0[m][3] - mnew);
                rs += (p0 + p1) + (p2 + p3);
                pf0[m] = pack4(p0, p1, p2, p3);
            }
            rs += __shfl_xor(rs, 16);
            rs += __shfl_xor(rs, 32);
            if (!noresc) {
                float al = exp2_raw(m0 - mnew);
                m0 = mnew;
                l0 *= al;
#pragma unroll
                for (int dt = 0; dt < 4; dt++) o0[dt] *= al;
            }
            l0 += rs;
        }
        {
            float mx = max16(s1);
            mx = fmaxf(mx, __shfl_xor(mx, 16));
            mx = fmaxf(mx, __shfl_xor(mx, 32));
            const bool noresc = __all(mx <= m1 + 8.0f);
            const float mnew = noresc ? m1 : fmaxf(m1, mx);
            float rs = 0.f;
#pragma unroll
            for (int m = 0; m < 4; m++) {
                float p0 = exp2_raw(s1[m][0] - mnew);
                float p1 = exp2_raw(s1[m][1] - mnew);
                float p2 = exp2_raw(s1[m][2] - mnew);
                float p3 = exp2_raw(s1[m][3] - mnew);
                rs += (p0 + p1) + (p2 + p3);
                pf1[m] = pack4(p0, p1, p2, p3);
            }
            rs += __shfl_xor(rs, 16);
            rs += __shfl_xor(rs, 32);
            if (!noresc) {
                float al = exp2_raw(m1 - mnew);
                m1 = mnew;
                l1 *= al;
#pragma unroll
                for (int dt = 0; dt < 4; dt++) o1[dt] *= al;
            }
            l1 += rs;
        }

        // ---- O^T += V^T * P^T : V-frags shared across both q-groups ----
        __builtin_amdgcn_s_setprio(1);
#pragma unroll
        for (int dt = 0; dt < 4; dt++) {
            const _Float16* vr = &Vt[dt * 16 + lc][quad * 4];
#pragma unroll
            for (int m = 0; m < 4; m++) {
                half4 va = *(const half4*)(vr + m * 16);  // keys m*16+quad*4+{0..3}
                o0[dt] = __builtin_amdgcn_mfma_f32_16x16x16f16(va, pf0[m], o0[dt], 0, 0, 0);
                o1[dt] = __builtin_amdgcn_mfma_f32_16x16x16f16(va, pf1[m], o1[dt], 0, 0, 0);
            }
        }
        __builtin_amdgcn_s_setprio(0);
    }

    // epilogue: O^T reg (dt, r) -> dim = dt*16 + quad*4 + r, t = q{0,1}row
    const int b = bh >> 4, h = bh & 15;
    {
        float inv = __builtin_amdgcn_rcpf(l0);
        size_t base = ((size_t)(b * TT + q0row)) * CC + h * HD;
#pragma unroll
        for (int dt = 0; dt < 4; dt++) {
            half4 hv;
#pragma unroll
            for (int r = 0; r < 4; r++) hv[r] = (_Float16)(o0[dt][r] * inv);
            *(half4*)(Op + base + dt * 16 + quad * 4) = hv;
        }
    }
    {
        float inv = __builtin_amdgcn_rcpf(l1);
        size_t base = ((size_t)(b * TT + q1row)) * CC + h * HD;
#pragma unroll
        for (int dt = 0; dt < 4; dt++) {
            half4 hv;
#pragma unroll
            for (int r = 0; r < 4; r++) hv[r] = (_Float16)(o1[dt][r] * inv);
            *(half4*)(Op + base + dt * 16 + quad * 4) = hv;
        }
    }
}

// ---------------------------------------------------------------------------
extern "C" void kernel_launch(void* const* d_in, const int* in_sizes, int n_in,
                              void* d_out, int out_size, void* d_ws, size_t ws_size,
                              hipStream_t stream) {
    const float* x      = (const float*)d_in[0];  // [B,T,C]
    const float* W_attn = (const float*)d_in[1];  // [3C,C]
    const float* b_attn = (const float*)d_in[2];  // [3C]
    const float* W_proj = (const float*)d_in[3];  // [C,C]
    const float* b_proj = (const float*)d_in[4];  // [C]
    float* out = (float*)d_out;

    const size_t SZ_XH  = (size_t)BB * TT * CC * 2;
    const size_t SZ_WA  = (size_t)3 * CC * CC * 2;
    const size_t SZ_WP  = (size_t)CC * CC * 2;
    const size_t SZ_QKV = (size_t)BB * HH * TT * HD * 2;
    size_t off = 0;
    _Float16* xh  = (_Float16*)((char*)d_ws + off); off += SZ_XH;
    _Float16* wah = (_Float16*)((char*)d_ws + off); off += SZ_WA;
    _Float16* wph = (_Float16*)((char*)d_ws + off); off += SZ_WP;
    _Float16* Qh  = (_Float16*)((char*)d_ws + off); off += SZ_QKV;
    _Float16* Kh  = (_Float16*)((char*)d_ws + off); off += SZ_QKV;
    _Float16* Vh  = (_Float16*)((char*)d_ws + off); off += SZ_QKV;
    _Float16* Ah  = (_Float16*)((char*)d_ws + off); off += SZ_XH;
    if (ws_size < off) return;

    const int NX  = BB * TT * CC;
    const int NWA = 3 * CC * CC;
    const int NWP = CC * CC;
    cvt_f32_f16<<<NX / 8 / 256, 256, 0, stream>>>(x, xh, NX);
    cvt_f32_f16<<<NWA / 8 / 256, 256, 0, stream>>>(W_attn, wah, NWA);
    cvt_f32_f16<<<NWP / 8 / 256, 256, 0, stream>>>(W_proj, wph, NWP);

    hgemm_nt<0><<<dim3(3 * CC / 128, BB * TT / 128), 256, 0, stream>>>(
        xh, wah, b_attn, Qh, Kh, Vh, nullptr, BB * TT, 3 * CC, CC);

    attn_flash<<<dim3(BB * HH, TT / 256), 512, 0, stream>>>(Qh, Kh, Vh, Ah);

    hgemm_nt<1><<<dim3(CC / 128, BB * TT / 128), 256, 0, stream>>>(
        Ah, wph, b_proj, nullptr, nullptr, nullptr, out, BB * TT, CC, CC);
}

// Round 5
// 288.500 us; speedup vs baseline: 1.1652x; 1.0116x over previous
//
#include <hip/hip_runtime.h>
#include <hip/hip_bf16.h>

// Problem constants (B=4, T=2048, C=1024, H=16, HD=64)
#define BB 4
#define TT 2048
#define CC 1024
#define HH 16
#define HD 64

typedef _Float16 half8 __attribute__((ext_vector_type(8)));
typedef _Float16 half4 __attribute__((ext_vector_type(4)));
typedef _Float16 half2_t __attribute__((ext_vector_type(2)));
typedef __fp16 fp16x2 __attribute__((ext_vector_type(2)));
typedef float floatx4 __attribute__((ext_vector_type(4)));
typedef float floatx16 __attribute__((ext_vector_type(16)));
typedef int intx2 __attribute__((ext_vector_type(2)));
typedef int intx4 __attribute__((ext_vector_type(4)));

// async global->LDS, 16B per lane (dest = wave-uniform base + lane*16)
__device__ __forceinline__ void async_cp16(const void* g, void* l) {
    __builtin_amdgcn_global_load_lds(
        (const __attribute__((address_space(1))) unsigned int*)g,
        (__attribute__((address_space(3))) unsigned int*)l,
        16, 0, 0);
}

// raw v_exp_f32 — args <= 8 (defer-max THR) so no overflow; very negative
// args underflow to 0 in HW which is exactly softmax semantics.
__device__ __forceinline__ float exp2_raw(float x) {
    return __builtin_amdgcn_exp2f(x);
}

// pack 2 f32 -> dword of 2 fp16 via v_cvt_pkrtz
__device__ __forceinline__ int pkh(float a, float b) {
    fp16x2 v = __builtin_amdgcn_cvt_pkrtz(a, b);
    return __builtin_bit_cast(int, v);
}

// pack 4 f32 -> half4 (GEMM epilogue-free; kept for attn-free paths)
__device__ __forceinline__ half4 pack4(float p0, float p1, float p2, float p3) {
    fp16x2 lo = __builtin_amdgcn_cvt_pkrtz(p0, p1);
    fp16x2 hi = __builtin_amdgcn_cvt_pkrtz(p2, p3);
    return __builtin_bit_cast(half4, __builtin_shufflevector(lo, hi, 0, 1, 2, 3));
}

// max over a f32x16 accumulator, max3-friendly
__device__ __forceinline__ float maxv16(floatx16 s) {
    float a0 = fmaxf(fmaxf(s[0], s[1]), s[2]);
    float a1 = fmaxf(fmaxf(s[3], s[4]), s[5]);
    float a2 = fmaxf(fmaxf(s[6], s[7]), s[8]);
    float a3 = fmaxf(fmaxf(s[9], s[10]), s[11]);
    float a4 = fmaxf(fmaxf(s[12], s[13]), s[14]);
    float b0 = fmaxf(fmaxf(a0, a1), a2);
    float b1 = fmaxf(fmaxf(a3, a4), s[15]);
    return fmaxf(b0, b1);
}

// Assemble one 16-key B-frag (32x32x16, 8 fp16) from 4 cvtpk dwords.
// Inputs (per T12/m214 verified layout): a={lo:(k0,k1),hi:(k4,k5)},
// b={lo:(k2,k3),hi:(k6,k7)}, c={lo:(k8,k9),hi:(k12,k13)}, d={lo:(k10,k11),hi:(k14,k15)}
// permlane32_swap(x,y): swaps x's hi 32 lanes with y's lo 32 lanes ->
// r[0]={lo:x_lo,hi:y_lo}, r[1]={lo:x_hi,hi:y_hi}.
__device__ __forceinline__ half8 assembleF(int a, int b, int c, int d) {
    intx2 s1 = __builtin_amdgcn_permlane32_swap(a, c, false, false);
    intx2 s2 = __builtin_amdgcn_permlane32_swap(b, d, false, false);
    intx4 w = {s1[0], s2[0], s1[1], s2[1]};
    return __builtin_bit_cast(half8, w);
}

// ---------------------------------------------------------------------------
// fp32 -> fp16 conversion, 8 elements/thread
// ---------------------------------------------------------------------------
__global__ void cvt_f32_f16(const float* __restrict__ src, _Float16* __restrict__ dst, int n) {
    int i = (blockIdx.x * blockDim.x + threadIdx.x) * 8;
    if (i < n) {
        float4 v0 = *(const float4*)(src + i);
        float4 v1 = *(const float4*)(src + i + 4);
        half8 h;
        h[0] = (_Float16)v0.x; h[1] = (_Float16)v0.y; h[2] = (_Float16)v0.z; h[3] = (_Float16)v0.w;
        h[4] = (_Float16)v1.x; h[5] = (_Float16)v1.y; h[6] = (_Float16)v1.z; h[7] = (_Float16)v1.w;
        *(half8*)(dst + i) = h;
    }
}

// ---------------------------------------------------------------------------
// NT GEMM: 128x128 tile, BK=64 (known-good from round 4)
// ---------------------------------------------------------------------------
template <int EPI>
__global__ __launch_bounds__(256) void hgemm_nt(
    const _Float16* __restrict__ A, const _Float16* __restrict__ Bw,
    const float* __restrict__ bias,
    _Float16* __restrict__ q_out, _Float16* __restrict__ k_out, _Float16* __restrict__ v_out,
    float* __restrict__ c_out,
    int M, int N, int K)
{
    __shared__ __attribute__((aligned(16))) _Float16 As[2 * 128 * 32];  // 16KB
    __shared__ __attribute__((aligned(16))) _Float16 Bs[2 * 128 * 32];  // 16KB

    const int tid  = threadIdx.x;
    const int lane = tid & 63;
    const int wave = tid >> 6;
    const int quad = lane >> 4;
    const int lc   = lane & 15;
    const int wr   = wave >> 1, wc = wave & 1;
    const size_t bm = (size_t)blockIdx.y * 128;
    const size_t bn = (size_t)blockIdx.x * 128;

    const int r0 = tid >> 2;        // 0..63
    const int ck = (tid & 3) * 8;   // 0,8,16,24

    const _Float16* Ap = A + (bm + r0) * (size_t)K + ck;
    const _Float16* Bp = Bw + (bn + r0) * (size_t)K + ck;
    _Float16* lA = As + tid * 8;
    _Float16* lB = Bs + tid * 8;
    const size_t rstep = (size_t)64 * K;

    floatx4 acc[4][4] = {};

    for (int kk = 0; kk < K; kk += 64) {
        __syncthreads();
        async_cp16(Ap + kk, lA);
        async_cp16(Ap + kk + rstep, lA + 2048);
        async_cp16(Ap + kk + 32, lA + 4096);
        async_cp16(Ap + kk + 32 + rstep, lA + 4096 + 2048);
        async_cp16(Bp + kk, lB);
        async_cp16(Bp + kk + rstep, lB + 2048);
        async_cp16(Bp + kk + 32, lB + 4096);
        async_cp16(Bp + kk + 32 + rstep, lB + 4096 + 2048);
        __syncthreads();

#pragma unroll
        for (int h = 0; h < 2; h++) {
            half8 af[4], bf[4];
#pragma unroll
            for (int mt = 0; mt < 4; mt++)
                af[mt] = *(const half8*)(As + h * 4096 + (wr * 64 + mt * 16 + lc) * 32 + quad * 8);
#pragma unroll
            for (int nt = 0; nt < 4; nt++)
                bf[nt] = *(const half8*)(Bs + h * 4096 + (wc * 64 + nt * 16 + lc) * 32 + quad * 8);
#pragma unroll
            for (int mt = 0; mt < 4; mt++)
#pragma unroll
                for (int nt = 0; nt < 4; nt++)
                    acc[mt][nt] = __builtin_amdgcn_mfma_f32_16x16x32_f16(af[mt], bf[nt], acc[mt][nt], 0, 0, 0);
        }
    }

#pragma unroll
    for (int mt = 0; mt < 4; mt++) {
        int mbase = (int)bm + wr * 64 + mt * 16 + quad * 4;
#pragma unroll
        for (int nt = 0; nt < 4; nt++) {
            int n = (int)bn + wc * 64 + nt * 16 + lc;
            float bv = bias[n];
#pragma unroll
            for (int r = 0; r < 4; r++) {
                float v = acc[mt][nt][r] + bv;
                int mm = mbase + r;
                if (EPI == 0) {
                    int seg = n >> 10;        // 0=Q 1=K 2=V
                    int cm  = n & 1023;
                    int h = cm >> 6, d = cm & 63;
                    int bb = mm >> 11, t = mm & 2047;
                    size_t dst = (((size_t)(bb * HH + h)) * TT + t) * HD + d;
                    if (seg == 0)      q_out[dst] = (_Float16)(v * 0.18033688f);
                    else if (seg == 1) k_out[dst] = (_Float16)v;
                    else               v_out[dst] = (_Float16)v;
                } else {
                    c_out[(size_t)mm * N + n] = v;
                }
            }
        }
    }
}

// ---------------------------------------------------------------------------
// Flash attention, 32x32 MFMA structure (HK/m214 port, S^T formulation).
// Grid (B*H, T/256), 512 thr = 8 waves, 32 queries/wave, key tile = 64.
//  S^T = K*Q^T via mfma_f32_32x32x16_f16: C col=lane&31=q, rows = 32 keys
//    in regs -> softmax is in-register + ONE shfl_xor(32).
//  P^T -> B-frags via cvt_pkrtz + permlane32_swap (T12).
//  O^T += V^T*P^T via mfma_f32_32x32x16_f16 (8 MFMA/tile vs 32 at 16x16x16).
// LDS: Ks/Vt linear [64][64] + XOR swizzle byte^=(row&7)<<4 (G4).
// K staged with pre-permuted source column -> linear conflict-free ds_writes.
// ---------------------------------------------------------------------------
__global__ __launch_bounds__(512) void attn_flash(
    const _Float16* __restrict__ Qp, const _Float16* __restrict__ Kp,
    const _Float16* __restrict__ Vp, _Float16* __restrict__ Op)
{
    __shared__ __attribute__((aligned(16))) _Float16 Ks[64 * 64];  // [key][dim] 8KB
    __shared__ __attribute__((aligned(16))) _Float16 Vt[64 * 64];  // [dim][key] 8KB

    const int bh   = blockIdx.x;   // 0..63 (b*16+h)
    const int qt   = blockIdx.y;   // 0..7
    const int tid  = threadIdx.x;
    const int lane = tid & 63;
    const int wave = tid >> 6;     // 0..7
    const int ql   = lane & 31;    // query (and dim-row id)
    const int hi   = lane >> 5;    // 0/1

    const size_t hb = (size_t)bh * TT * HD;

    // Q regs: B-frag B[k=dim][n=q]: n=lane&31, k=(lane>>5)*8+j per 16-chunk
    const int qrow = qt * 256 + wave * 32 + ql;
    half8 bq[4];
#pragma unroll
    for (int c = 0; c < 4; c++)
        bq[c] = *(const half8*)(Qp + hb + (size_t)qrow * HD + c * 16 + hi * 8);

    floatx16 o0 = (floatx16)0.0f, o1 = (floatx16)0.0f;  // O^T dims 0-31 / 32-63
    float mrun = -1e30f, lrun = 0.f;

    // staging maps (512 threads)
    const int sk = tid >> 3;           // K: key 0..63
    const int sj = tid & 7;            // K: dest 16B slot
    const int sg = sj ^ (sk & 7);      // K: source col chunk (pre-swizzled)
    const _Float16* Kg = Kp + hb + (size_t)sk * HD + sg * 8;
    _Float16* KsW = Ks + tid * 8;      // linear dest -> conflict-free write

    const int vkp = tid >> 4;          // V: key pair 0..31
    const int vd4 = (tid & 15) * 4;    // V: dim group 0..60
    const _Float16* Vg0 = Vp + hb + (size_t)(2 * vkp) * HD + vd4;
    const _Float16* Vg1 = Vg0 + HD;

    for (int kt = 0; kt < TT; kt += 64) {
        const size_t koff = (size_t)kt * HD;
        half8 kv  = *(const half8*)(Kg + koff);
        half4 va0 = *(const half4*)(Vg0 + koff);
        half4 vb0 = *(const half4*)(Vg1 + koff);
        __syncthreads();  // previous tile fully consumed
        *(half8*)KsW = kv;
#pragma unroll
        for (int j = 0; j < 4; j++) {
            int row = vd4 + j;
            int boff = (row * 128 + vkp * 4) ^ ((row & 7) << 4);
            half2_t w; w[0] = va0[j]; w[1] = vb0[j];
            *(half2_t*)((char*)Vt + boff) = w;
        }
        __syncthreads();  // staging visible

        // ---- S^T = K * Q^T : 2 key-blocks x 4 dim-chunks, 32x32x16 ----
        floatx16 s0 = (floatx16)0.0f, s1 = (floatx16)0.0f;
        __builtin_amdgcn_s_setprio(1);
#pragma unroll
        for (int c = 0; c < 4; c++) {
            int offk = (ql * 128 + c * 32 + hi * 16) ^ ((ql & 7) << 4);
            half8 a0 = *(const half8*)((const char*)Ks + offk);
            half8 a1 = *(const half8*)((const char*)Ks + offk + 4096);
            s0 = __builtin_amdgcn_mfma_f32_32x32x16_f16(a0, bq[c], s0, 0, 0, 0);
            s1 = __builtin_amdgcn_mfma_f32_32x32x16_f16(a1, bq[c], s1, 0, 0, 0);
        }
        __builtin_amdgcn_s_setprio(0);

        // ---- online softmax: per-lane 32 keys for query q=lane&31 ----
        float mx = fmaxf(maxv16(s0), maxv16(s1));
        mx = fmaxf(mx, __shfl_xor(mx, 32));
        const bool noresc = __all(mx <= mrun + 8.0f);
        const float mnew = noresc ? mrun : fmaxf(mrun, mx);
        float rs = 0.f;
        int d[16];
#pragma unroll
        for (int i = 0; i < 8; i++) {
            float e0 = exp2_raw(s0[2 * i] - mnew);
            float e1 = exp2_raw(s0[2 * i + 1] - mnew);
            rs += e0 + e1;
            d[i] = pkh(e0, e1);
        }
#pragma unroll
        for (int i = 0; i < 8; i++) {
            float e0 = exp2_raw(s1[2 * i] - mnew);
            float e1 = exp2_raw(s1[2 * i + 1] - mnew);
            rs += e0 + e1;
            d[8 + i] = pkh(e0, e1);
        }
        rs += __shfl_xor(rs, 32);
        if (!noresc) {
            float al = exp2_raw(mrun - mnew);
            mrun = mnew;
            lrun *= al;
            o0 *= al;
            o1 *= al;
        }
        lrun += rs;

        // ---- P^T B-frags: 16 keys each, via permlane32_swap ----
        half8 F[4];
        F[0] = assembleF(d[0], d[1], d[2], d[3]);      // keys 0-15
        F[1] = assembleF(d[4], d[5], d[6], d[7]);      // keys 16-31
        F[2] = assembleF(d[8], d[9], d[10], d[11]);    // keys 32-47
        F[3] = assembleF(d[12], d[13], d[14], d[15]);  // keys 48-63

        // ---- O^T += V^T * P^T : 2 dim-blocks x 4 key-chunks, 32x32x16 ----
        __builtin_amdgcn_s_setprio(1);
#pragma unroll
        for (int kb = 0; kb < 4; kb++) {
            int offv = (ql * 128 + kb * 32 + hi * 16) ^ ((ql & 7) << 4);
            half8 v0 = *(const half8*)((const char*)Vt + offv);
            half8 v1 = *(const half8*)((const char*)Vt + offv + 4096);
            o0 = __builtin_amdgcn_mfma_f32_32x32x16_f16(v0, F[kb], o0, 0, 0, 0);
            o1 = __builtin_amdgcn_mfma_f32_32x32x16_f16(v1, F[kb], o1, 0, 0, 0);
        }
        __builtin_amdgcn_s_setprio(0);
    }

    // epilogue: O^T reg r (per dim-block) -> dim = (r&3) + 8*(r>>2) + 4*hi
    const float inv = __builtin_amdgcn_rcpf(lrun);
    const int b = bh >> 4, h = bh & 15;
    size_t base = ((size_t)(b * TT + qrow)) * CC + h * HD;
#pragma unroll
    for (int rr = 0; rr < 4; rr++) {
        half4 hv0, hv1;
#pragma unroll
        for (int t = 0; t < 4; t++) {
            hv0[t] = (_Float16)(o0[rr * 4 + t] * inv);
            hv1[t] = (_Float16)(o1[rr * 4 + t] * inv);
        }
        *(half4*)(Op + base + 8 * rr + 4 * hi) = hv0;
        *(half4*)(Op + base + 32 + 8 * rr + 4 * hi) = hv1;
    }
}

// ---------------------------------------------------------------------------
extern "C" void kernel_launch(void* const* d_in, const int* in_sizes, int n_in,
                              void* d_out, int out_size, void* d_ws, size_t ws_size,
                              hipStream_t stream) {
    const float* x      = (const float*)d_in[0];  // [B,T,C]
    const float* W_attn = (const float*)d_in[1];  // [3C,C]
    const float* b_attn = (const float*)d_in[2];  // [3C]
    const float* W_proj = (const float*)d_in[3];  // [C,C]
    const float* b_proj = (const float*)d_in[4];  // [C]
    float* out = (float*)d_out;

    const size_t SZ_XH  = (size_t)BB * TT * CC * 2;
    const size_t SZ_WA  = (size_t)3 * CC * CC * 2;
    const size_t SZ_WP  = (size_t)CC * CC * 2;
    const size_t SZ_QKV = (size_t)BB * HH * TT * HD * 2;
    size_t off = 0;
    _Float16* xh  = (_Float16*)((char*)d_ws + off); off += SZ_XH;
    _Float16* wah = (_Float16*)((char*)d_ws + off); off += SZ_WA;
    _Float16* wph = (_Float16*)((char*)d_ws + off); off += SZ_WP;
    _Float16* Qh  = (_Float16*)((char*)d_ws + off); off += SZ_QKV;
    _Float16* Kh  = (_Float16*)((char*)d_ws + off); off += SZ_QKV;
    _Float16* Vh  = (_Float16*)((char*)d_ws + off); off += SZ_QKV;
    _Float16* Ah  = (_Float16*)((char*)d_ws + off); off += SZ_XH;
    if (ws_size < off) return;

    const int NX  = BB * TT * CC;
    const int NWA = 3 * CC * CC;
    const int NWP = CC * CC;
    cvt_f32_f16<<<NX / 8 / 256, 256, 0, stream>>>(x, xh, NX);
    cvt_f32_f16<<<NWA / 8 / 256, 256, 0, stream>>>(W_attn, wah, NWA);
    cvt_f32_f16<<<NWP / 8 / 256, 256, 0, stream>>>(W_proj, wph, NWP);

    hgemm_nt<0><<<dim3(3 * CC / 128, BB * TT / 128), 256, 0, stream>>>(
        xh, wah, b_attn, Qh, Kh, Vh, nullptr, BB * TT, 3 * CC, CC);

    attn_flash<<<dim3(BB * HH, TT / 256), 512, 0, stream>>>(Qh, Kh, Vh, Ah);

    hgemm_nt<1><<<dim3(CC / 128, BB * TT / 128), 256, 0, stream>>>(
        Ah, wph, b_proj, nullptr, nullptr, nullptr, out, BB * TT, CC, CC);
}

// Round 6
// 276.248 us; speedup vs baseline: 1.2169x; 1.0443x over previous
//
#include <hip/hip_runtime.h>
#include <hip/hip_bf16.h>

// Problem constants (B=4, T=2048, C=1024, H=16, HD=64)
#define BB 4
#define TT 2048
#define CC 1024
#define HH 16
#define HD 64

typedef _Float16 half8 __attribute__((ext_vector_type(8)));
typedef _Float16 half4 __attribute__((ext_vector_type(4)));
typedef _Float16 half2_t __attribute__((ext_vector_type(2)));
typedef __fp16 fp16x2 __attribute__((ext_vector_type(2)));
typedef float floatx4 __attribute__((ext_vector_type(4)));
typedef float floatx16 __attribute__((ext_vector_type(16)));
typedef int intx2 __attribute__((ext_vector_type(2)));
typedef int intx4 __attribute__((ext_vector_type(4)));

// async global->LDS, 16B per lane (dest = wave-uniform base + lane*16)
__device__ __forceinline__ void async_cp16(const void* g, void* l) {
    __builtin_amdgcn_global_load_lds(
        (const __attribute__((address_space(1))) unsigned int*)g,
        (__attribute__((address_space(3))) unsigned int*)l,
        16, 0, 0);
}

// raw v_exp_f32 — args <= 8 (defer-max THR) so no overflow; very negative
// args underflow to 0 in HW which is exactly softmax semantics.
__device__ __forceinline__ float exp2_raw(float x) {
    return __builtin_amdgcn_exp2f(x);
}

// pack 2 f32 -> dword of 2 fp16 via v_cvt_pkrtz
__device__ __forceinline__ int pkh(float a, float b) {
    fp16x2 v = __builtin_amdgcn_cvt_pkrtz(a, b);
    return __builtin_bit_cast(int, v);
}

// max over a f32x16 accumulator, max3-friendly
__device__ __forceinline__ float maxv16(floatx16 s) {
    float a0 = fmaxf(fmaxf(s[0], s[1]), s[2]);
    float a1 = fmaxf(fmaxf(s[3], s[4]), s[5]);
    float a2 = fmaxf(fmaxf(s[6], s[7]), s[8]);
    float a3 = fmaxf(fmaxf(s[9], s[10]), s[11]);
    float a4 = fmaxf(fmaxf(s[12], s[13]), s[14]);
    float b0 = fmaxf(fmaxf(a0, a1), a2);
    float b1 = fmaxf(fmaxf(a3, a4), s[15]);
    return fmaxf(b0, b1);
}

// Assemble one 16-key B-frag (32x32x16, 8 fp16) from 4 cvtpk dwords.
// (verified in round 5: passed absmax)
__device__ __forceinline__ half8 assembleF(int a, int b, int c, int d) {
    intx2 s1 = __builtin_amdgcn_permlane32_swap(a, c, false, false);
    intx2 s2 = __builtin_amdgcn_permlane32_swap(b, d, false, false);
    intx4 w = {s1[0], s2[0], s1[1], s2[1]};
    return __builtin_bit_cast(half8, w);
}

// ---------------------------------------------------------------------------
// fp32 -> fp16 conversion, 8 elements/thread
// ---------------------------------------------------------------------------
__global__ void cvt_f32_f16(const float* __restrict__ src, _Float16* __restrict__ dst, int n) {
    int i = (blockIdx.x * blockDim.x + threadIdx.x) * 8;
    if (i < n) {
        float4 v0 = *(const float4*)(src + i);
        float4 v1 = *(const float4*)(src + i + 4);
        half8 h;
        h[0] = (_Float16)v0.x; h[1] = (_Float16)v0.y; h[2] = (_Float16)v0.z; h[3] = (_Float16)v0.w;
        h[4] = (_Float16)v1.x; h[5] = (_Float16)v1.y; h[6] = (_Float16)v1.z; h[7] = (_Float16)v1.w;
        *(half8*)(dst + i) = h;
    }
}

// ---------------------------------------------------------------------------
// NT GEMM: 128x128 tile, BK=64 (known-good from round 4)
// ---------------------------------------------------------------------------
template <int EPI>
__global__ __launch_bounds__(256) void hgemm_nt(
    const _Float16* __restrict__ A, const _Float16* __restrict__ Bw,
    const float* __restrict__ bias,
    _Float16* __restrict__ q_out, _Float16* __restrict__ k_out, _Float16* __restrict__ v_out,
    float* __restrict__ c_out,
    int M, int N, int K)
{
    __shared__ __attribute__((aligned(16))) _Float16 As[2 * 128 * 32];  // 16KB
    __shared__ __attribute__((aligned(16))) _Float16 Bs[2 * 128 * 32];  // 16KB

    const int tid  = threadIdx.x;
    const int lane = tid & 63;
    const int wave = tid >> 6;
    const int quad = lane >> 4;
    const int lc   = lane & 15;
    const int wr   = wave >> 1, wc = wave & 1;
    const size_t bm = (size_t)blockIdx.y * 128;
    const size_t bn = (size_t)blockIdx.x * 128;

    const int r0 = tid >> 2;        // 0..63
    const int ck = (tid & 3) * 8;   // 0,8,16,24

    const _Float16* Ap = A + (bm + r0) * (size_t)K + ck;
    const _Float16* Bp = Bw + (bn + r0) * (size_t)K + ck;
    _Float16* lA = As + tid * 8;
    _Float16* lB = Bs + tid * 8;
    const size_t rstep = (size_t)64 * K;

    floatx4 acc[4][4] = {};

    for (int kk = 0; kk < K; kk += 64) {
        __syncthreads();
        async_cp16(Ap + kk, lA);
        async_cp16(Ap + kk + rstep, lA + 2048);
        async_cp16(Ap + kk + 32, lA + 4096);
        async_cp16(Ap + kk + 32 + rstep, lA + 4096 + 2048);
        async_cp16(Bp + kk, lB);
        async_cp16(Bp + kk + rstep, lB + 2048);
        async_cp16(Bp + kk + 32, lB + 4096);
        async_cp16(Bp + kk + 32 + rstep, lB + 4096 + 2048);
        __syncthreads();

#pragma unroll
        for (int h = 0; h < 2; h++) {
            half8 af[4], bf[4];
#pragma unroll
            for (int mt = 0; mt < 4; mt++)
                af[mt] = *(const half8*)(As + h * 4096 + (wr * 64 + mt * 16 + lc) * 32 + quad * 8);
#pragma unroll
            for (int nt = 0; nt < 4; nt++)
                bf[nt] = *(const half8*)(Bs + h * 4096 + (wc * 64 + nt * 16 + lc) * 32 + quad * 8);
#pragma unroll
            for (int mt = 0; mt < 4; mt++)
#pragma unroll
                for (int nt = 0; nt < 4; nt++)
                    acc[mt][nt] = __builtin_amdgcn_mfma_f32_16x16x32_f16(af[mt], bf[nt], acc[mt][nt], 0, 0, 0);
        }
    }

#pragma unroll
    for (int mt = 0; mt < 4; mt++) {
        int mbase = (int)bm + wr * 64 + mt * 16 + quad * 4;
#pragma unroll
        for (int nt = 0; nt < 4; nt++) {
            int n = (int)bn + wc * 64 + nt * 16 + lc;
            float bv = bias[n];
#pragma unroll
            for (int r = 0; r < 4; r++) {
                float v = acc[mt][nt][r] + bv;
                int mm = mbase + r;
                if (EPI == 0) {
                    int seg = n >> 10;        // 0=Q 1=K 2=V
                    int cm  = n & 1023;
                    int h = cm >> 6, d = cm & 63;
                    int bb = mm >> 11, t = mm & 2047;
                    size_t dst = (((size_t)(bb * HH + h)) * TT + t) * HD + d;
                    if (seg == 0)      q_out[dst] = (_Float16)(v * 0.18033688f);
                    else if (seg == 1) k_out[dst] = (_Float16)v;
                    else               v_out[dst] = (_Float16)v;
                } else {
                    c_out[(size_t)mm * N + n] = v;
                }
            }
        }
    }
}

// ---------------------------------------------------------------------------
// Flash attention, 32x32 MFMA structure. Grid (B*H, T/256), 512 thr = 8
// waves, 32 queries/wave, key tile = 64.
// Round 6 changes vs round 5:
//  - T14 prefetch: next tile's K/V loaded into regs right after the staging
//    barrier; consumed at the NEXT tile's ds_write -> compute covers the
//    global-load latency (was fully exposed between the two barriers).
//  - Vt swizzle g(row)=(row>>2)&7 (was (row&7)): write rows are 4*(tid&15)+j
//    so (row>>2) carries the per-lane bits -> V-write is now 2 lanes/bank
//    (free); read stays ~4-way (best achievable with row-only swizzle).
// ---------------------------------------------------------------------------
__global__ __launch_bounds__(512) void attn_flash(
    const _Float16* __restrict__ Qp, const _Float16* __restrict__ Kp,
    const _Float16* __restrict__ Vp, _Float16* __restrict__ Op)
{
    __shared__ __attribute__((aligned(16))) _Float16 Ks[64 * 64];  // [key][dim] 8KB
    __shared__ __attribute__((aligned(16))) _Float16 Vt[64 * 64];  // [dim][key] 8KB

    const int bh   = blockIdx.x;   // 0..63 (b*16+h)
    const int qt   = blockIdx.y;   // 0..7
    const int tid  = threadIdx.x;
    const int lane = tid & 63;
    const int wave = tid >> 6;     // 0..7
    const int ql   = lane & 31;    // query (and dim-row id)
    const int hi   = lane >> 5;    // 0/1

    const size_t hb = (size_t)bh * TT * HD;

    // Q regs: B-frag B[k=dim][n=q]: n=lane&31, k=(lane>>5)*8+j per 16-chunk
    const int qrow = qt * 256 + wave * 32 + ql;
    half8 bq[4];
#pragma unroll
    for (int c = 0; c < 4; c++)
        bq[c] = *(const half8*)(Qp + hb + (size_t)qrow * HD + c * 16 + hi * 8);

    floatx16 o0 = (floatx16)0.0f, o1 = (floatx16)0.0f;  // O^T dims 0-31 / 32-63
    float mrun = -1e30f, lrun = 0.f;

    // staging maps (512 threads)
    const int sk = tid >> 3;           // K: key 0..63
    const int sj = tid & 7;            // K: dest 16B slot
    const int sg = sj ^ (sk & 7);      // K: source col chunk (pre-swizzled)
    const _Float16* Kg = Kp + hb + (size_t)sk * HD + sg * 8;
    _Float16* KsW = Ks + tid * 8;      // linear dest -> conflict-free write

    const int vkp = tid >> 4;          // V: key pair 0..31
    const int vd4 = (tid & 15) * 4;    // V: dim group 0..60
    const _Float16* Vg0 = Vp + hb + (size_t)(2 * vkp) * HD + vd4;
    const _Float16* Vg1 = Vg0 + HD;

    // T14 prologue: tile 0 K/V into regs
    half8 kv  = *(const half8*)Kg;
    half4 va0 = *(const half4*)Vg0;
    half4 vb0 = *(const half4*)Vg1;

    for (int kt = 0; kt < TT; kt += 64) {
        __syncthreads();  // previous tile fully consumed
        *(half8*)KsW = kv;
#pragma unroll
        for (int j = 0; j < 4; j++) {
            int row = vd4 + j;
            int boff = (row * 128 + vkp * 4) ^ (((row >> 2) & 7) << 4);
            half2_t w; w[0] = va0[j]; w[1] = vb0[j];
            *(half2_t*)((char*)Vt + boff) = w;
        }
        __syncthreads();  // staging visible

        // T14: issue next tile's loads now; consumed at next tile's ds_write
        if (kt + 64 < TT) {
            const size_t koff = (size_t)(kt + 64) * HD;
            kv  = *(const half8*)(Kg + koff);
            va0 = *(const half4*)(Vg0 + koff);
            vb0 = *(const half4*)(Vg1 + koff);
        }

        // ---- S^T = K * Q^T : 2 key-blocks x 4 dim-chunks, 32x32x16 ----
        floatx16 s0 = (floatx16)0.0f, s1 = (floatx16)0.0f;
        __builtin_amdgcn_s_setprio(1);
#pragma unroll
        for (int c = 0; c < 4; c++) {
            int offk = (ql * 128 + c * 32 + hi * 16) ^ ((ql & 7) << 4);
            half8 a0 = *(const half8*)((const char*)Ks + offk);
            half8 a1 = *(const half8*)((const char*)Ks + offk + 4096);
            s0 = __builtin_amdgcn_mfma_f32_32x32x16_f16(a0, bq[c], s0, 0, 0, 0);
            s1 = __builtin_amdgcn_mfma_f32_32x32x16_f16(a1, bq[c], s1, 0, 0, 0);
        }
        __builtin_amdgcn_s_setprio(0);

        // ---- online softmax: per-lane 32 keys for query q=lane&31 ----
        float mx = fmaxf(maxv16(s0), maxv16(s1));
        mx = fmaxf(mx, __shfl_xor(mx, 32));
        const bool noresc = __all(mx <= mrun + 8.0f);
        const float mnew = noresc ? mrun : fmaxf(mrun, mx);
        float rs = 0.f;
        int d[16];
#pragma unroll
        for (int i = 0; i < 8; i++) {
            float e0 = exp2_raw(s0[2 * i] - mnew);
            float e1 = exp2_raw(s0[2 * i + 1] - mnew);
            rs += e0 + e1;
            d[i] = pkh(e0, e1);
        }
#pragma unroll
        for (int i = 0; i < 8; i++) {
            float e0 = exp2_raw(s1[2 * i] - mnew);
            float e1 = exp2_raw(s1[2 * i + 1] - mnew);
            rs += e0 + e1;
            d[8 + i] = pkh(e0, e1);
        }
        rs += __shfl_xor(rs, 32);
        if (!noresc) {
            float al = exp2_raw(mrun - mnew);
            mrun = mnew;
            lrun *= al;
            o0 *= al;
            o1 *= al;
        }
        lrun += rs;

        // ---- P^T B-frags: 16 keys each, via permlane32_swap ----
        half8 F[4];
        F[0] = assembleF(d[0], d[1], d[2], d[3]);      // keys 0-15
        F[1] = assembleF(d[4], d[5], d[6], d[7]);      // keys 16-31
        F[2] = assembleF(d[8], d[9], d[10], d[11]);    // keys 32-47
        F[3] = assembleF(d[12], d[13], d[14], d[15]);  // keys 48-63

        // ---- O^T += V^T * P^T : 2 dim-blocks x 4 key-chunks, 32x32x16 ----
        __builtin_amdgcn_s_setprio(1);
#pragma unroll
        for (int kb = 0; kb < 4; kb++) {
            int offv = (ql * 128 + kb * 32 + hi * 16) ^ (((ql >> 2) & 7) << 4);
            half8 v0 = *(const half8*)((const char*)Vt + offv);
            half8 v1 = *(const half8*)((const char*)Vt + offv + 4096);
            o0 = __builtin_amdgcn_mfma_f32_32x32x16_f16(v0, F[kb], o0, 0, 0, 0);
            o1 = __builtin_amdgcn_mfma_f32_32x32x16_f16(v1, F[kb], o1, 0, 0, 0);
        }
        __builtin_amdgcn_s_setprio(0);
    }

    // epilogue: O^T reg r (per dim-block) -> dim = (r&3) + 8*(r>>2) + 4*hi
    const float inv = __builtin_amdgcn_rcpf(lrun);
    const int b = bh >> 4, h = bh & 15;
    size_t base = ((size_t)(b * TT + qrow)) * CC + h * HD;
#pragma unroll
    for (int rr = 0; rr < 4; rr++) {
        half4 hv0, hv1;
#pragma unroll
        for (int t = 0; t < 4; t++) {
            hv0[t] = (_Float16)(o0[rr * 4 + t] * inv);
            hv1[t] = (_Float16)(o1[rr * 4 + t] * inv);
        }
        *(half4*)(Op + base + 8 * rr + 4 * hi) = hv0;
        *(half4*)(Op + base + 32 + 8 * rr + 4 * hi) = hv1;
    }
}

// ---------------------------------------------------------------------------
extern "C" void kernel_launch(void* const* d_in, const int* in_sizes, int n_in,
                              void* d_out, int out_size, void* d_ws, size_t ws_size,
                              hipStream_t stream) {
    const float* x      = (const float*)d_in[0];  // [B,T,C]
    const float* W_attn = (const float*)d_in[1];  // [3C,C]
    const float* b_attn = (const float*)d_in[2];  // [3C]
    const float* W_proj = (const float*)d_in[3];  // [C,C]
    const float* b_proj = (const float*)d_in[4];  // [C]
    float* out = (float*)d_out;

    const size_t SZ_XH  = (size_t)BB * TT * CC * 2;
    const size_t SZ_WA  = (size_t)3 * CC * CC * 2;
    const size_t SZ_WP  = (size_t)CC * CC * 2;
    const size_t SZ_QKV = (size_t)BB * HH * TT * HD * 2;
    size_t off = 0;
    _Float16* xh  = (_Float16*)((char*)d_ws + off); off += SZ_XH;
    _Float16* wah = (_Float16*)((char*)d_ws + off); off += SZ_WA;
    _Float16* wph = (_Float16*)((char*)d_ws + off); off += SZ_WP;
    _Float16* Qh  = (_Float16*)((char*)d_ws + off); off += SZ_QKV;
    _Float16* Kh  = (_Float16*)((char*)d_ws + off); off += SZ_QKV;
    _Float16* Vh  = (_Float16*)((char*)d_ws + off); off += SZ_QKV;
    _Float16* Ah  = (_Float16*)((char*)d_ws + off); off += SZ_XH;
    if (ws_size < off) return;

    const int NX  = BB * TT * CC;
    const int NWA = 3 * CC * CC;
    const int NWP = CC * CC;
    cvt_f32_f16<<<NX / 8 / 256, 256, 0, stream>>>(x, xh, NX);
    cvt_f32_f16<<<NWA / 8 / 256, 256, 0, stream>>>(W_attn, wah, NWA);
    cvt_f32_f16<<<NWP / 8 / 256, 256, 0, stream>>>(W_proj, wph, NWP);

    hgemm_nt<0><<<dim3(3 * CC / 128, BB * TT / 128), 256, 0, stream>>>(
        xh, wah, b_attn, Qh, Kh, Vh, nullptr, BB * TT, 3 * CC, CC);

    attn_flash<<<dim3(BB * HH, TT / 256), 512, 0, stream>>>(Qh, Kh, Vh, Ah);

    hgemm_nt<1><<<dim3(CC / 128, BB * TT / 128), 256, 0, stream>>>(
        Ah, wph, b_proj, nullptr, nullptr, nullptr, out, BB * TT, CC, CC);
}